// Round 7
// baseline (118.615 us; speedup 1.0000x reference)
//
#include <hip/hip_runtime.h>
#include <hip/hip_fp16.h>

#define D_VOCAB 262
#define D_EMB   128
#define KW      5
#define NCHAR   16
#define NKO     (KW * D_EMB)      // 640 halfs per vocab row (1280 B)

// d_ws layout:
//   P  at offset 0       : 262*640 halfs = 335,360 B (fp16 table, P[v][k][o])
//   Wt at offset 335,872 : 640*128 floats = 327,680 B (transposed conv_w)

// ---------------------------------------------------------------------------
// Stage 1: Wt[(k*128+o)*128 + i] = conv_w[o*640 + i*5 + k]. Coalesced reads,
// scattered dword writes (320 KB, L2 absorbs). No LDS, no barriers. ~2 us.
// ---------------------------------------------------------------------------
__global__ __launch_bounds__(256) void transpose_w_kernel(
    const float* __restrict__ cw, float* __restrict__ Wt) {
  const int gid = blockIdx.x * 256 + threadIdx.x;   // 0..81919
  const float val = cw[gid];
  const int o = gid / 640;
  const int r = gid - o * 640;
  const int i = r / 5;
  const int k = r - i * 5;
  Wt[(k * D_EMB + o) * D_EMB + i] = val;
}

// ---------------------------------------------------------------------------
// Stage 2: P[v][ko] = sum_i emb[v][i] * Wt[ko][i], fp16. One lane per (v,ko):
// 32 float4 loads of L2-resident Wt + 128 FMA; emb row wave-uniform (scalar
// loads). 2620 waves, no barriers. ~8-12 us.
// ---------------------------------------------------------------------------
__global__ __launch_bounds__(256) void compute_P_kernel(
    const float* __restrict__ emb, const float* __restrict__ Wt,
    __half* __restrict__ P) {
  const int wave = threadIdx.x >> 6;
  const int lane = threadIdx.x & 63;
  const int w = blockIdx.x * 4 + wave;      // 0..2619
  const int v = w / 10;                     // vocab id (wave-uniform)
  const int ko = (w - v * 10) * 64 + lane;  // k*128 + o

  const float* er = emb + v * D_EMB;
  const float4* wt = (const float4*)(Wt + ko * D_EMB);
  float acc = 0.f;
#pragma unroll 8
  for (int i4 = 0; i4 < 32; ++i4) {
    const float4 wv = wt[i4];
    acc += er[i4 * 4 + 0] * wv.x + er[i4 * 4 + 1] * wv.y +
           er[i4 * 4 + 2] * wv.z + er[i4 * 4 + 3] * wv.w;
  }
  P[v * NKO + ko] = __float2half(acc);
}

// ---------------------------------------------------------------------------
// Main: 2 seqs/wave, 32 lanes/seq, 4 ch/lane. Per (j,k) tap: ONE
// global_load_dwordx2 (512 B/wave = both seqs' full k-row, zero waste) +
// 2x v_pk_add_f16 into a rolling 5-slot window; fp32 max at slot completion.
// No LDS, no barriers; 16384 waves.
// ID layout: lanes 0..31 load the pair's 32 ids (seq n0 chars 0-15, then
// seq n0+1 chars 0-15); lanes 32..63 load the SAME addresses (broadcast).
// __shfl(myid, half*16 + j) then yields id[j] of seq n0+half for every lane.
// ---------------------------------------------------------------------------
__global__ __launch_bounds__(256) void conv_char_main_kernel(
    const int* __restrict__ ids, const __half* __restrict__ P,
    const float* __restrict__ bias, float* __restrict__ out, int n_seq) {
  const int lane = threadIdx.x & 63;
  const int w = (blockIdx.x * 256 + threadIdx.x) >> 6;   // global wave id
  const int n0 = w * 2;                   // first seq of the pair
  const int half = lane >> 5;             // 0: seq n0, 1: seq n0+1
  const int l5 = lane & 31;
  const int o = l5 * 4;                   // this lane's 4 channels

  // pair's 32 ids in lanes 0..31; lanes 32..63 hold a broadcast copy
  const int myid = ids[(size_t)n0 * NCHAR + l5];

  const __half2 hz = __float2half2_rn(0.f);
  __half2 win[5][2];
#pragma unroll
  for (int s = 0; s < 5; ++s) { win[s][0] = hz; win[s][1] = hz; }
  float vmax[4] = {-1e30f, -1e30f, -1e30f, -1e30f};

#pragma unroll
  for (int j = 0; j < NCHAR; ++j) {
    const int id = __shfl(myid, half * NCHAR + j);   // this half's id[j]
    const uint2* rp = (const uint2*)(P + (size_t)id * NKO) + l5;
#pragma unroll
    for (int k = 0; k < KW; ++k) {
      const int cc = j + 2 - k;                      // output position fed
      if (cc >= 0 && cc < NCHAR) {
        const uint2 rv = rp[k * 32];                 // dwordx2, imm offset
        __half2* ws = win[cc % 5];
        ws[0] = __hadd2(ws[0], *(const __half2*)&rv.x);
        ws[1] = __hadd2(ws[1], *(const __half2*)&rv.y);
      }
    }
    if (j >= 2) {                                    // y[j-2] complete
      const int s = (j - 2) % 5;
      const float2 f0 = __half22float2(win[s][0]);
      const float2 f1 = __half22float2(win[s][1]);
      vmax[0] = fmaxf(vmax[0], f0.x); vmax[1] = fmaxf(vmax[1], f0.y);
      vmax[2] = fmaxf(vmax[2], f1.x); vmax[3] = fmaxf(vmax[3], f1.y);
      win[s][0] = hz; win[s][1] = hz;
    }
  }
#pragma unroll
  for (int cc = 14; cc < 16; ++cc) {
    const int s = cc % 5;
    const float2 f0 = __half22float2(win[s][0]);
    const float2 f1 = __half22float2(win[s][1]);
    vmax[0] = fmaxf(vmax[0], f0.x); vmax[1] = fmaxf(vmax[1], f0.y);
    vmax[2] = fmaxf(vmax[2], f1.x); vmax[3] = fmaxf(vmax[3], f1.y);
  }

  const int n = n0 + half;
  if (n < n_seq) {
    const float4 bv = *(const float4*)(bias + o);
    float4 r;
    r.x = vmax[0] + bv.x; r.y = vmax[1] + bv.y;
    r.z = vmax[2] + bv.z; r.w = vmax[3] + bv.w;
    *(float4*)(out + (size_t)n * D_EMB + o) = r;   // 512 B/half-wave, coalesced
  }
}

// ---------------------------------------------------------------------------
// Inputs: d_in[0] ids (B*W*C int32), d_in[1] lengths (unused),
//         d_in[2] emb (262x128 f32), d_in[3] conv_w (128x128x5 f32),
//         d_in[4] conv_b (128 f32).  Output: (B*W*128) f32.
// ---------------------------------------------------------------------------
extern "C" void kernel_launch(void* const* d_in, const int* in_sizes, int n_in,
                              void* d_out, int out_size, void* d_ws, size_t ws_size,
                              hipStream_t stream) {
  const int*   input = (const int*)d_in[0];
  const float* emb   = (const float*)d_in[2];
  const float* cw    = (const float*)d_in[3];
  const float* cb    = (const float*)d_in[4];
  float* out = (float*)d_out;

  __half* P  = (__half*)d_ws;
  float*  Wt = (float*)((char*)d_ws + 335872);

  const int n_seq = in_sizes[0] / NCHAR;   // B*W = 32768

  transpose_w_kernel<<<320, 256, 0, stream>>>(cw, Wt);    // 81,920 elems
  compute_P_kernel<<<655, 256, 0, stream>>>(emb, Wt, P);  // 2,620 waves

  const int nwaves = (n_seq + 1) / 2;                     // 16,384
  const int blocks = (nwaves + 3) / 4;                    // 4,096 (4 waves/blk)
  conv_char_main_kernel<<<blocks, 256, 0, stream>>>(input, P, cb, out, n_seq);
}

// Round 8
// 96.250 us; speedup vs baseline: 1.2324x; 1.2324x over previous
//
#include <hip/hip_runtime.h>
#include <hip/hip_fp16.h>

#define D_VOCAB 262
#define D_EMB   128
#define KW      5
#define NCHAR   16
#define NKO     (KW * D_EMB)      // 640 halfs per vocab row (1280 B)

typedef _Float16 h8 __attribute__((ext_vector_type(8)));
typedef float    f8 __attribute__((ext_vector_type(8)));

// d_ws layout:
//   P   at offset 0       : 262*640 halfs = 335,360 B (fp16 table, P[v][k][o])
//   Wt2 at offset 335,872 : 128*640 floats = 327,680 B, Wt2[i][ko]

// ---------------------------------------------------------------------------
// Stage 1: Wt2[i*640 + k*128 + o] = conv_w[o*640 + i*5 + k]. Coalesced dword
// reads, scattered dword writes (320 KB, L2 absorbs). No LDS/barriers. ~2 us.
// ---------------------------------------------------------------------------
__global__ __launch_bounds__(256) void transpose_w_kernel(
    const float* __restrict__ cw, float* __restrict__ Wt2) {
  const int gid = blockIdx.x * 256 + threadIdx.x;   // 0..81919
  const float val = cw[gid];
  const int o = gid / 640;
  const int r = gid - o * 640;
  const int i = r / 5;
  const int k = r - i * 5;
  Wt2[i * NKO + k * D_EMB + o] = val;
}

// ---------------------------------------------------------------------------
// Stage 2: P[v][ko] = sum_i emb[v][i] * Wt2[i][ko], fp16. One block per v,
// 640 threads (t = ko). emb row staged in LDS (broadcast reads = free);
// Wt2 loads are lane-consecutive dwords -> fully coalesced 256 B/wave-instr
// of an L2-resident 320 KB array. 262 blocks x 10 waves. ~5 us.
// ---------------------------------------------------------------------------
__global__ __launch_bounds__(640) void compute_P_kernel(
    const float* __restrict__ emb, const float* __restrict__ Wt2,
    __half* __restrict__ P) {
  __shared__ float emb_s[D_EMB];
  const int v = blockIdx.x;
  const int t = threadIdx.x;            // ko
  if (t < D_EMB) emb_s[t] = emb[v * D_EMB + t];
  __syncthreads();

  float acc = 0.f;
#pragma unroll 16
  for (int i = 0; i < D_EMB; ++i) {
    acc += emb_s[i] * Wt2[i * NKO + t];
  }
  P[v * NKO + t] = __float2half(acc);
}

// ---------------------------------------------------------------------------
// Main (R4 structure — fastest measured variant, ~30 us): 4 seqs/wave,
// 16 lanes/seq, 8 channels/lane. Per (j,k) tap: ONE 16 B load (8 halfs) +
// 4x v_pk_add_f16 into a rolling 5-slot window; packed max at completion.
// No LDS, no barriers.
// ---------------------------------------------------------------------------
__global__ __launch_bounds__(256) void conv_char_main_kernel(
    const int* __restrict__ ids, const _Float16* __restrict__ P,
    const float* __restrict__ bias, float* __restrict__ out) {
  const int lane = threadIdx.x & 63;
  const int wave = threadIdx.x >> 6;
  const int n_base = (blockIdx.x * 4 + wave) * 4;  // 4 seqs per wave
  const int g4 = lane & 48;                        // seq-group * 16
  const int s = lane & 15;
  const int o = s * 8;                             // this lane's 8 channels
  const int n = n_base + (lane >> 4);

  // the wave's 64 ids (4 seqs x 16 chars), coalesced
  const int myid = ids[n_base * NCHAR + lane];

  h8 win[5];
#pragma unroll
  for (int w = 0; w < 5; ++w) win[w] = (h8)(_Float16)0.f;
  h8 vmax = (h8)(_Float16)(-60000.f);

#pragma unroll
  for (int j = 0; j < NCHAR; ++j) {
    const int id = __shfl(myid, g4 + j);           // broadcast within group
    const _Float16* row = P + (size_t)id * NKO + o;
#pragma unroll
    for (int k = 0; k < KW; ++k) {
      const int c = j + 2 - k;                     // output position fed
      if (c >= 0 && c < NCHAR) {
        const h8 val = *(const h8*)(row + k * D_EMB);   // 16 B load
        win[c % 5] += val;                              // 4x v_pk_add_f16
      }
    }
    if (j >= 2) {                                  // y[j-2] complete
      const int w = (j - 2) % 5;
      vmax = __builtin_elementwise_max(vmax, win[w]);   // 4x v_pk_max_f16
      win[w] = (h8)(_Float16)0.f;
    }
  }
  vmax = __builtin_elementwise_max(vmax, win[14 % 5]);
  vmax = __builtin_elementwise_max(vmax, win[15 % 5]);

  const f8 fv = __builtin_convertvector(vmax, f8);
  const f8 bv = *(const f8*)(bias + o);
  const f8 r = fv + bv;
  *(f8*)(out + (size_t)n * D_EMB + o) = r;
}

// ---------------------------------------------------------------------------
// Inputs: d_in[0] ids (B*W*C int32), d_in[1] lengths (unused),
//         d_in[2] emb (262x128 f32), d_in[3] conv_w (128x128x5 f32),
//         d_in[4] conv_b (128 f32).  Output: (B*W*128) f32.
// ---------------------------------------------------------------------------
extern "C" void kernel_launch(void* const* d_in, const int* in_sizes, int n_in,
                              void* d_out, int out_size, void* d_ws, size_t ws_size,
                              hipStream_t stream) {
  const int*   input = (const int*)d_in[0];
  const float* emb   = (const float*)d_in[2];
  const float* cw    = (const float*)d_in[3];
  const float* cb    = (const float*)d_in[4];
  float* out = (float*)d_out;

  _Float16* P   = (_Float16*)d_ws;
  float*    Wt2 = (float*)((char*)d_ws + 335872);

  const int n_seq = in_sizes[0] / NCHAR;   // B*W = 32768

  transpose_w_kernel<<<320, 256, 0, stream>>>(cw, Wt2);         // 81,920 elems
  compute_P_kernel<<<D_VOCAB, 640, 0, stream>>>(emb, Wt2, (__half*)P);

  const int blocks = n_seq / 16;           // 4 waves/block, 4 seqs/wave
  conv_char_main_kernel<<<blocks, 256, 0, stream>>>(input, P, cb, out);
}